// Round 3
// baseline (1778.020 us; speedup 1.0000x reference)
//
#include <hip/hip_runtime.h>
#include <math.h>

#define C 64           // feature width for all layers
#define NEG_SLOPE 0.2f
#define LDP 68         // padded LDS row stride (floats): 68*4=272B, 16B-aligned

// ---- K0: wv[k] = sum_c W[k][c] * att[c]  (folds W_dst @ att_dst) ----
__global__ void k_wvec(const float* __restrict__ W, const float* __restrict__ att,
                       float* __restrict__ wv) {
    int k = threadIdx.x;  // 64 threads
    float s = 0.f;
    #pragma unroll
    for (int c = 0; c < C; ++c) s = fmaf(W[k * C + c], att[c], s);
    wv[k] = s;
}

// ---- K1: register-tiled dual GEMM per 64-node block:
//   xs  = x @ W_src ; outbuf = x @ W_lin + b_conv + b_lin
//   a_s = xs . att_src ; a_d = x . wd
// threads: 256 = (ty 0..15) x (tx 0..15); thread tile: 4 rows x 4 cols x 2 mats
__global__ __launch_bounds__(256) void k_transform(
    const float* __restrict__ x,
    const float* __restrict__ Wsrc,
    const float* __restrict__ Wlin,
    const float* __restrict__ att_src,
    const float* __restrict__ wd,
    const float* __restrict__ b_conv,
    const float* __restrict__ b_lin,
    float* __restrict__ xs,
    float* __restrict__ a_s,
    float* __restrict__ a_d,
    float* __restrict__ outbuf,
    int nNodes)
{
    __shared__ float sWs[C * LDP];
    __shared__ float sWl[C * LDP];
    __shared__ float sx[C * LDP];

    const int tid = threadIdx.x;
    const int tx = tid & 15;        // col group
    const int ty = tid >> 4;        // row group
    const int n0 = blockIdx.x * 64; // first node of this block

    // stage W matrices (64x64, coalesced float4)
    #pragma unroll
    for (int j = 0; j < 4; ++j) {
        int idx = tid + j * 256;            // 1024 float4 slots
        int r = idx >> 4, q = idx & 15;
        *(float4*)&sWs[r * LDP + q * 4] = *(const float4*)&Wsrc[r * C + q * 4];
        *(float4*)&sWl[r * LDP + q * 4] = *(const float4*)&Wlin[r * C + q * 4];
    }
    // stage x tile (64 rows)
    #pragma unroll
    for (int j = 0; j < 4; ++j) {
        int idx = tid + j * 256;
        int r = idx >> 4, q = idx & 15;
        int n = n0 + r;
        float4 v = make_float4(0.f, 0.f, 0.f, 0.f);
        if (n < nNodes) v = *(const float4*)&x[(size_t)n * C + q * 4];
        *(float4*)&sx[r * LDP + q * 4] = v;
    }
    __syncthreads();

    float accS[4][4] = {};
    float accL[4][4] = {};
    float ad[4] = {};
    float xrv[4][4];
    float wsv[4][4], wlv[4][4], wdv[4];

    #pragma unroll
    for (int k0 = 0; k0 < C; k0 += 4) {
        #pragma unroll
        for (int r = 0; r < 4; ++r)
            *(float4*)xrv[r] = *(const float4*)&sx[(ty * 4 + r) * LDP + k0];
        #pragma unroll
        for (int kk = 0; kk < 4; ++kk) {
            *(float4*)wsv[kk] = *(const float4*)&sWs[(k0 + kk) * LDP + tx * 4];
            *(float4*)wlv[kk] = *(const float4*)&sWl[(k0 + kk) * LDP + tx * 4];
            wdv[kk] = wd[k0 + kk];
        }
        #pragma unroll
        for (int kk = 0; kk < 4; ++kk) {
            #pragma unroll
            for (int r = 0; r < 4; ++r) {
                float xv = xrv[r][kk];
                ad[r] = fmaf(xv, wdv[kk], ad[r]);
                #pragma unroll
                for (int c = 0; c < 4; ++c) {
                    accS[r][c] = fmaf(xv, wsv[kk][c], accS[r][c]);
                    accL[r][c] = fmaf(xv, wlv[kk][c], accL[r][c]);
                }
            }
        }
    }

    // epilogue
    float attv[4], bias[4];
    *(float4*)attv = *(const float4*)&att_src[tx * 4];
    {
        float4 bc = *(const float4*)&b_conv[tx * 4];
        float4 bl = *(const float4*)&b_lin[tx * 4];
        bias[0] = bc.x + bl.x; bias[1] = bc.y + bl.y;
        bias[2] = bc.z + bl.z; bias[3] = bc.w + bl.w;
    }

    #pragma unroll
    for (int r = 0; r < 4; ++r) {
        int n = n0 + ty * 4 + r;
        if (n >= nNodes) continue;
        float4 vs = make_float4(accS[r][0], accS[r][1], accS[r][2], accS[r][3]);
        float4 vl = make_float4(accL[r][0] + bias[0], accL[r][1] + bias[1],
                                accL[r][2] + bias[2], accL[r][3] + bias[3]);
        *(float4*)&xs[(size_t)n * C + tx * 4] = vs;
        *(float4*)&outbuf[(size_t)n * C + tx * 4] = vl;

        // a_s: reduce acc.att over the 16 tx lanes (consecutive lanes in wave)
        float p = accS[r][0] * attv[0] + accS[r][1] * attv[1]
                + accS[r][2] * attv[2] + accS[r][3] * attv[3];
        #pragma unroll
        for (int m = 8; m > 0; m >>= 1) p += __shfl_xor(p, m);
        if (tx == 0) {
            a_s[n] = p;
            a_d[n] = ad[r];   // identical across tx threads
        }
    }
}

// ============================ CSR build ============================

__global__ __launch_bounds__(256) void k_zero(int* __restrict__ p, int n) {
    for (int i = blockIdx.x * blockDim.x + threadIdx.x; i < n;
         i += gridDim.x * blockDim.x) p[i] = 0;
}

__global__ __launch_bounds__(256) void k_hist(const int* __restrict__ dst,
                                              int* __restrict__ cnt, int nE) {
    for (int e = blockIdx.x * blockDim.x + threadIdx.x; e < nE;
         e += gridDim.x * blockDim.x) atomicAdd(&cnt[dst[e]], 1);
}

// block-level scan: 256 threads x 4 elems = 1024 per block
__global__ __launch_bounds__(256) void k_scan_block(
    const int* __restrict__ cnt, int* __restrict__ rowptr,
    int* __restrict__ partials, int n)
{
    __shared__ int sdata[256];
    const int base = blockIdx.x * 1024;
    const int t = threadIdx.x;
    int v[4]; int s = 0;
    #pragma unroll
    for (int i = 0; i < 4; ++i) {
        int idx = base + t * 4 + i;
        v[i] = (idx < n) ? cnt[idx] : 0;
        s += v[i];
    }
    sdata[t] = s;
    __syncthreads();
    for (int off = 1; off < 256; off <<= 1) {
        int x = (t >= off) ? sdata[t - off] : 0;
        __syncthreads();
        sdata[t] += x;
        __syncthreads();
    }
    int run = sdata[t] - s;   // exclusive prefix of this thread
    #pragma unroll
    for (int i = 0; i < 4; ++i) {
        int idx = base + t * 4 + i;
        if (idx < n) rowptr[idx] = run;
        run += v[i];
    }
    if (t == 255) partials[blockIdx.x] = sdata[255];
}

// single-block exclusive scan of <=256 partials
__global__ __launch_bounds__(256) void k_scan_partials(int* __restrict__ partials, int nb) {
    __shared__ int sd[256];
    const int t = threadIdx.x;
    int v = (t < nb) ? partials[t] : 0;
    sd[t] = v;
    __syncthreads();
    for (int off = 1; off < 256; off <<= 1) {
        int x = (t >= off) ? sd[t - off] : 0;
        __syncthreads();
        sd[t] += x;
        __syncthreads();
    }
    if (t < nb) partials[t] = sd[t] - v;   // exclusive
}

__global__ __launch_bounds__(256) void k_scan_add(
    int* __restrict__ rowptr, int* __restrict__ cursor,
    const int* __restrict__ partials, int n, int nE)
{
    for (int i = blockIdx.x * blockDim.x + threadIdx.x; i < n;
         i += gridDim.x * blockDim.x) {
        int r = rowptr[i] + partials[i >> 10];
        rowptr[i] = r;
        cursor[i] = r;
    }
    if (blockIdx.x == 0 && threadIdx.x == 0) rowptr[n] = nE;
}

__global__ __launch_bounds__(256) void k_scatter(
    const int* __restrict__ src, const int* __restrict__ dst,
    int* __restrict__ cursor, int* __restrict__ csr_src, int nE)
{
    for (int e = blockIdx.x * blockDim.x + threadIdx.x; e < nE;
         e += gridDim.x * blockDim.x) {
        int pos = atomicAdd(&cursor[dst[e]], 1);
        csr_src[pos] = src[e];
    }
}

// ============== fused per-dst-node GAT aggregation ==============
__global__ __launch_bounds__(256) void k_gat_node(
    const int* __restrict__ rowptr, const int* __restrict__ csr_src,
    const float* __restrict__ a_s, const float* __restrict__ a_d,
    const float* __restrict__ xs, float* __restrict__ outbuf, int nNodes)
{
    const int lane = threadIdx.x & 63;
    const int n = (blockIdx.x * blockDim.x + threadIdx.x) >> 6;
    if (n >= nNodes) return;
    const int start = rowptr[n], end = rowptr[n + 1];
    if (start == end) return;            // keep the linear-skip part only
    const float a_dn = a_d[n];

    // pass 1: segment max
    float mloc = -INFINITY;
    for (int j = start + lane; j < end; j += 64) {
        float ev = a_s[csr_src[j]] + a_dn;
        ev = ev > 0.f ? ev : NEG_SLOPE * ev;
        mloc = fmaxf(mloc, ev);
    }
    #pragma unroll
    for (int m = 32; m > 0; m >>= 1) mloc = fmaxf(mloc, __shfl_xor(mloc, m));

    // pass 2+3
    float acc = 0.f;
    float sloc = 0.f;
    for (int jb = start; jb < end; jb += 64) {
        const int cnt = min(64, end - jb);
        float ex = 0.f; int sidx = 0;
        if (lane < cnt) {
            sidx = csr_src[jb + lane];
            float ev = a_s[sidx] + a_dn;
            ev = ev > 0.f ? ev : NEG_SLOPE * ev;
            ex = __expf(ev - mloc);
            sloc += ex;
        }
        int t = 0;
        for (; t + 1 < cnt; t += 2) {
            float w0 = __shfl(ex, t);     int s0 = __shfl(sidx, t);
            float w1 = __shfl(ex, t + 1); int s1 = __shfl(sidx, t + 1);
            float v0 = xs[(size_t)s0 * C + lane];
            float v1 = xs[(size_t)s1 * C + lane];
            acc = fmaf(w0, v0, acc);
            acc = fmaf(w1, v1, acc);
        }
        if (t < cnt) {
            float w0 = __shfl(ex, t); int s0 = __shfl(sidx, t);
            acc = fmaf(w0, xs[(size_t)s0 * C + lane], acc);
        }
    }
    #pragma unroll
    for (int m = 32; m > 0; m >>= 1) sloc += __shfl_xor(sloc, m);

    outbuf[(size_t)n * C + lane] += acc / sloc;
}

// ---- K5: row L2-normalize, in place ----
__global__ __launch_bounds__(256) void k_normalize(float* __restrict__ out, int nNodes)
{
    const int lane = threadIdx.x & 63;
    const int grp  = threadIdx.x >> 6;
    const int groups = gridDim.x * (blockDim.x >> 6);
    for (int n = blockIdx.x * (blockDim.x >> 6) + grp; n < nNodes; n += groups) {
        float v = out[(size_t)n * C + lane];
        float ss = v * v;
        #pragma unroll
        for (int m = 32; m > 0; m >>= 1) ss += __shfl_xor(ss, m);
        float nrm = fmaxf(sqrtf(ss), 1e-12f);
        out[(size_t)n * C + lane] = v / nrm;
    }
}

extern "C" void kernel_launch(void* const* d_in, const int* in_sizes, int n_in,
                              void* d_out, int out_size, void* d_ws, size_t ws_size,
                              hipStream_t stream) {
    const float* x  = (const float*)d_in[0];
    const int*   ei = (const int*)d_in[1];
    const int N = in_sizes[0] / C;
    const int E = in_sizes[1] / 2;
    const int* srcIdx = ei;
    const int* dstIdx = ei + E;

    // workspace layout
    char* w = (char*)d_ws;
    float* xs      = (float*)w; w += (size_t)N * C * 4;
    float* hbuf    = (float*)w; w += (size_t)N * C * 4;
    float* a_s     = (float*)w; w += (size_t)N * 4;
    float* a_d     = (float*)w; w += (size_t)N * 4;
    float* wvec    = (float*)w; w += C * 4;
    int*   dcount  = (int*)w;   w += (size_t)N * 4;
    int*   rowptr  = (int*)w;   w += ((size_t)N + 1) * 4;
    int*   cursor  = (int*)w;   w += (size_t)N * 4;
    int*   partials= (int*)w;   w += 256 * 4;
    int*   csr_src = (int*)w;   w += (size_t)E * 4;

    const float* Wsrc1 = (const float*)d_in[2];
    const float* Wdst1 = (const float*)d_in[3];
    const float* atts1 = (const float*)d_in[4];
    const float* attd1 = (const float*)d_in[5];
    const float* bcv1  = (const float*)d_in[6];
    const float* Wlin1 = (const float*)d_in[7];
    const float* blin1 = (const float*)d_in[8];
    const float* Wsrc2 = (const float*)d_in[9];
    const float* Wdst2 = (const float*)d_in[10];
    const float* atts2 = (const float*)d_in[11];
    const float* attd2 = (const float*)d_in[12];
    const float* bcv2  = (const float*)d_in[13];
    const float* Wlin2 = (const float*)d_in[14];
    const float* blin2 = (const float*)d_in[15];

    float* out = (float*)d_out;
    const int tblocks = (N + 63) / 64;
    const int nodeWaveBlocks = (N + 3) / 4;          // 1 wave per node, 4 waves/block
    const int nb = (N + 1023) / 1024;                // scan blocks (<=256 required)

    // ---------------- CSR build (per-call, deterministic) ----------------
    k_zero<<<512, 256, 0, stream>>>(dcount, N);
    k_hist<<<2048, 256, 0, stream>>>(dstIdx, dcount, E);
    k_scan_block<<<nb, 256, 0, stream>>>(dcount, rowptr, partials, N);
    k_scan_partials<<<1, 256, 0, stream>>>(partials, nb);
    k_scan_add<<<512, 256, 0, stream>>>(rowptr, cursor, partials, N, E);
    k_scatter<<<2048, 256, 0, stream>>>(srcIdx, dstIdx, cursor, csr_src, E);

    // ---------------- layer 1: x -> hbuf ----------------
    k_wvec<<<1, 64, 0, stream>>>(Wdst1, attd1, wvec);
    k_transform<<<tblocks, 256, 0, stream>>>(x, Wsrc1, Wlin1, atts1, wvec,
                                             bcv1, blin1, xs, a_s, a_d,
                                             hbuf, N);
    k_gat_node<<<nodeWaveBlocks, 256, 0, stream>>>(rowptr, csr_src, a_s, a_d,
                                                   xs, hbuf, N);

    // ---------------- layer 2: hbuf -> out ----------------
    k_wvec<<<1, 64, 0, stream>>>(Wdst2, attd2, wvec);
    k_transform<<<tblocks, 256, 0, stream>>>(hbuf, Wsrc2, Wlin2, atts2, wvec,
                                             bcv2, blin2, xs, a_s, a_d,
                                             out, N);
    k_gat_node<<<nodeWaveBlocks, 256, 0, stream>>>(rowptr, csr_src, a_s, a_d,
                                                   xs, out, N);

    // ---------------- final normalize ----------------
    k_normalize<<<1024, 256, 0, stream>>>(out, N);
}

// Round 4
// 1610.515 us; speedup vs baseline: 1.1040x; 1.1040x over previous
//
#include <hip/hip_runtime.h>
#include <math.h>

#define C 64           // feature width for all layers
#define NEG_SLOPE 0.2f
#define LDP 68         // padded LDS row stride (floats): 68*4=272B, 16B-aligned

// ---- K0: wv[k] = sum_c W[k][c] * att[c]  (folds W_dst @ att_dst) ----
__global__ void k_wvec(const float* __restrict__ W, const float* __restrict__ att,
                       float* __restrict__ wv) {
    int k = threadIdx.x;  // 64 threads
    float s = 0.f;
    #pragma unroll
    for (int c = 0; c < C; ++c) s = fmaf(W[k * C + c], att[c], s);
    wv[k] = s;
}

// ---- K1: register-tiled dual GEMM per 64-node block:
//   xs  = x @ W_src ; outbuf = x @ W_lin + b_conv + b_lin
//   a_s = xs . att_src ; a_d = x . wd
// threads: 256 = (ty 0..15) x (tx 0..15); thread tile: 4 rows x 4 cols x 2 mats
// NOTE: no local arrays / pointer punning — named float4 vars only (spill-proof).
__global__ __launch_bounds__(256) void k_transform(
    const float* __restrict__ x,
    const float* __restrict__ Wsrc,
    const float* __restrict__ Wlin,
    const float* __restrict__ att_src,
    const float* __restrict__ wd,
    const float* __restrict__ b_conv,
    const float* __restrict__ b_lin,
    float* __restrict__ xs,
    float* __restrict__ a_s,
    float* __restrict__ a_d,
    float* __restrict__ outbuf,
    int nNodes)
{
    __shared__ float sWs[C * LDP];
    __shared__ float sWl[C * LDP];
    __shared__ float sx[C * LDP];
    __shared__ float swd[C];

    const int tid = threadIdx.x;
    const int tx = tid & 15;        // col group
    const int ty = tid >> 4;        // row group
    const int tx4 = tx * 4;
    const int n0 = blockIdx.x * 64; // first node of this block

    if (tid < C) swd[tid] = wd[tid];
    // stage W matrices (64x64, coalesced float4)
    #pragma unroll
    for (int j = 0; j < 4; ++j) {
        int idx = tid + j * 256;            // 1024 float4 slots
        int r = idx >> 4, q = idx & 15;
        *(float4*)&sWs[r * LDP + q * 4] = *(const float4*)&Wsrc[r * C + q * 4];
        *(float4*)&sWl[r * LDP + q * 4] = *(const float4*)&Wlin[r * C + q * 4];
    }
    // stage x tile (64 rows)
    #pragma unroll
    for (int j = 0; j < 4; ++j) {
        int idx = tid + j * 256;
        int r = idx >> 4, q = idx & 15;
        int n = n0 + r;
        float4 v = make_float4(0.f, 0.f, 0.f, 0.f);
        if (n < nNodes) v = *(const float4*)&x[(size_t)n * C + q * 4];
        *(float4*)&sx[r * LDP + q * 4] = v;
    }
    __syncthreads();

    float4 accS0 = {0,0,0,0}, accS1 = {0,0,0,0}, accS2 = {0,0,0,0}, accS3 = {0,0,0,0};
    float4 accL0 = {0,0,0,0}, accL1 = {0,0,0,0}, accL2 = {0,0,0,0}, accL3 = {0,0,0,0};
    float ad0 = 0.f, ad1 = 0.f, ad2 = 0.f, ad3 = 0.f;

#define ROWFMA(XV, WS, WL, WDK, AS, AL, AD) \
    AD   = fmaf(XV, WDK,  AD);              \
    AS.x = fmaf(XV, WS.x, AS.x);            \
    AS.y = fmaf(XV, WS.y, AS.y);            \
    AS.z = fmaf(XV, WS.z, AS.z);            \
    AS.w = fmaf(XV, WS.w, AS.w);            \
    AL.x = fmaf(XV, WL.x, AL.x);            \
    AL.y = fmaf(XV, WL.y, AL.y);            \
    AL.z = fmaf(XV, WL.z, AL.z);            \
    AL.w = fmaf(XV, WL.w, AL.w);

#define KSUB(COMP, KOFF)                                            \
    {                                                               \
        float4 ws = *(const float4*)&sWs[(k0 + KOFF) * LDP + tx4];  \
        float4 wl = *(const float4*)&sWl[(k0 + KOFF) * LDP + tx4];  \
        float wdk = swd[k0 + KOFF];                                 \
        ROWFMA(xr0.COMP, ws, wl, wdk, accS0, accL0, ad0)            \
        ROWFMA(xr1.COMP, ws, wl, wdk, accS1, accL1, ad1)            \
        ROWFMA(xr2.COMP, ws, wl, wdk, accS2, accL2, ad2)            \
        ROWFMA(xr3.COMP, ws, wl, wdk, accS3, accL3, ad3)            \
    }

    #pragma unroll
    for (int k0 = 0; k0 < C; k0 += 4) {
        float4 xr0 = *(const float4*)&sx[(ty * 4 + 0) * LDP + k0];
        float4 xr1 = *(const float4*)&sx[(ty * 4 + 1) * LDP + k0];
        float4 xr2 = *(const float4*)&sx[(ty * 4 + 2) * LDP + k0];
        float4 xr3 = *(const float4*)&sx[(ty * 4 + 3) * LDP + k0];
        KSUB(x, 0)
        KSUB(y, 1)
        KSUB(z, 2)
        KSUB(w, 3)
    }
#undef KSUB
#undef ROWFMA

    // epilogue
    float4 attv = *(const float4*)&att_src[tx4];
    float4 bc = *(const float4*)&b_conv[tx4];
    float4 bl = *(const float4*)&b_lin[tx4];
    float4 bias = make_float4(bc.x + bl.x, bc.y + bl.y, bc.z + bl.z, bc.w + bl.w);

#define EPI(R, AS, AL, AD)                                                     \
    {                                                                          \
        int n = n0 + ty * 4 + R;                                               \
        if (n < nNodes) {                                                      \
            float4 vl = make_float4(AL.x + bias.x, AL.y + bias.y,              \
                                    AL.z + bias.z, AL.w + bias.w);             \
            *(float4*)&xs[(size_t)n * C + tx4] = AS;                           \
            *(float4*)&outbuf[(size_t)n * C + tx4] = vl;                       \
            float p = AS.x * attv.x + AS.y * attv.y                            \
                    + AS.z * attv.z + AS.w * attv.w;                           \
            p += __shfl_xor(p, 8); p += __shfl_xor(p, 4);                      \
            p += __shfl_xor(p, 2); p += __shfl_xor(p, 1);                      \
            if (tx == 0) { a_s[n] = p; a_d[n] = AD; }                          \
        }                                                                      \
    }

    EPI(0, accS0, accL0, ad0)
    EPI(1, accS1, accL1, ad1)
    EPI(2, accS2, accL2, ad2)
    EPI(3, accS3, accL3, ad3)
#undef EPI
}

// ============================ CSR build ============================

__global__ __launch_bounds__(256) void k_zero(int* __restrict__ p, int n) {
    for (int i = blockIdx.x * blockDim.x + threadIdx.x; i < n;
         i += gridDim.x * blockDim.x) p[i] = 0;
}

__global__ __launch_bounds__(256) void k_hist(const int* __restrict__ dst,
                                              int* __restrict__ cnt, int nE) {
    for (int e = blockIdx.x * blockDim.x + threadIdx.x; e < nE;
         e += gridDim.x * blockDim.x) atomicAdd(&cnt[dst[e]], 1);
}

// block-level scan: 256 threads x 4 elems = 1024 per block
__global__ __launch_bounds__(256) void k_scan_block(
    const int* __restrict__ cnt, int* __restrict__ rowptr,
    int* __restrict__ partials, int n)
{
    __shared__ int sdata[256];
    const int base = blockIdx.x * 1024;
    const int t = threadIdx.x;
    int v[4]; int s = 0;
    #pragma unroll
    for (int i = 0; i < 4; ++i) {
        int idx = base + t * 4 + i;
        v[i] = (idx < n) ? cnt[idx] : 0;
        s += v[i];
    }
    sdata[t] = s;
    __syncthreads();
    for (int off = 1; off < 256; off <<= 1) {
        int x = (t >= off) ? sdata[t - off] : 0;
        __syncthreads();
        sdata[t] += x;
        __syncthreads();
    }
    int run = sdata[t] - s;   // exclusive prefix of this thread
    #pragma unroll
    for (int i = 0; i < 4; ++i) {
        int idx = base + t * 4 + i;
        if (idx < n) rowptr[idx] = run;
        run += v[i];
    }
    if (t == 255) partials[blockIdx.x] = sdata[255];
}

// single-block exclusive scan of <=256 partials
__global__ __launch_bounds__(256) void k_scan_partials(int* __restrict__ partials, int nb) {
    __shared__ int sd[256];
    const int t = threadIdx.x;
    int v = (t < nb) ? partials[t] : 0;
    sd[t] = v;
    __syncthreads();
    for (int off = 1; off < 256; off <<= 1) {
        int x = (t >= off) ? sd[t - off] : 0;
        __syncthreads();
        sd[t] += x;
        __syncthreads();
    }
    if (t < nb) partials[t] = sd[t] - v;   // exclusive
}

__global__ __launch_bounds__(256) void k_scan_add(
    int* __restrict__ rowptr, int* __restrict__ cursor,
    const int* __restrict__ partials, int n, int nE)
{
    for (int i = blockIdx.x * blockDim.x + threadIdx.x; i < n;
         i += gridDim.x * blockDim.x) {
        int r = rowptr[i] + partials[i >> 10];
        rowptr[i] = r;
        cursor[i] = r;
    }
    if (blockIdx.x == 0 && threadIdx.x == 0) rowptr[n] = nE;
}

__global__ __launch_bounds__(256) void k_scatter(
    const int* __restrict__ src, const int* __restrict__ dst,
    int* __restrict__ cursor, int* __restrict__ csr_src, int nE)
{
    for (int e = blockIdx.x * blockDim.x + threadIdx.x; e < nE;
         e += gridDim.x * blockDim.x) {
        int pos = atomicAdd(&cursor[dst[e]], 1);
        csr_src[pos] = src[e];
    }
}

// ============== fused per-dst-node GAT aggregation ==============
__global__ __launch_bounds__(256) void k_gat_node(
    const int* __restrict__ rowptr, const int* __restrict__ csr_src,
    const float* __restrict__ a_s, const float* __restrict__ a_d,
    const float* __restrict__ xs, float* __restrict__ outbuf, int nNodes)
{
    const int lane = threadIdx.x & 63;
    const int n = (blockIdx.x * blockDim.x + threadIdx.x) >> 6;
    if (n >= nNodes) return;
    const int start = rowptr[n], end = rowptr[n + 1];
    if (start == end) return;            // keep the linear-skip part only
    const float a_dn = a_d[n];

    // pass 1: segment max
    float mloc = -INFINITY;
    for (int j = start + lane; j < end; j += 64) {
        float ev = a_s[csr_src[j]] + a_dn;
        ev = ev > 0.f ? ev : NEG_SLOPE * ev;
        mloc = fmaxf(mloc, ev);
    }
    #pragma unroll
    for (int m = 32; m > 0; m >>= 1) mloc = fmaxf(mloc, __shfl_xor(mloc, m));

    // pass 2+3
    float acc = 0.f;
    float sloc = 0.f;
    for (int jb = start; jb < end; jb += 64) {
        const int cnt = min(64, end - jb);
        float ex = 0.f; int sidx = 0;
        if (lane < cnt) {
            sidx = csr_src[jb + lane];
            float ev = a_s[sidx] + a_dn;
            ev = ev > 0.f ? ev : NEG_SLOPE * ev;
            ex = __expf(ev - mloc);
            sloc += ex;
        }
        int t = 0;
        for (; t + 1 < cnt; t += 2) {
            float w0 = __shfl(ex, t);     int s0 = __shfl(sidx, t);
            float w1 = __shfl(ex, t + 1); int s1 = __shfl(sidx, t + 1);
            float v0 = xs[(size_t)s0 * C + lane];
            float v1 = xs[(size_t)s1 * C + lane];
            acc = fmaf(w0, v0, acc);
            acc = fmaf(w1, v1, acc);
        }
        if (t < cnt) {
            float w0 = __shfl(ex, t); int s0 = __shfl(sidx, t);
            acc = fmaf(w0, xs[(size_t)s0 * C + lane], acc);
        }
    }
    #pragma unroll
    for (int m = 32; m > 0; m >>= 1) sloc += __shfl_xor(sloc, m);

    outbuf[(size_t)n * C + lane] += acc / sloc;
}

// ---- K5: row L2-normalize, in place ----
__global__ __launch_bounds__(256) void k_normalize(float* __restrict__ out, int nNodes)
{
    const int lane = threadIdx.x & 63;
    const int grp  = threadIdx.x >> 6;
    const int groups = gridDim.x * (blockDim.x >> 6);
    for (int n = blockIdx.x * (blockDim.x >> 6) + grp; n < nNodes; n += groups) {
        float v = out[(size_t)n * C + lane];
        float ss = v * v;
        #pragma unroll
        for (int m = 32; m > 0; m >>= 1) ss += __shfl_xor(ss, m);
        float nrm = fmaxf(sqrtf(ss), 1e-12f);
        out[(size_t)n * C + lane] = v / nrm;
    }
}

extern "C" void kernel_launch(void* const* d_in, const int* in_sizes, int n_in,
                              void* d_out, int out_size, void* d_ws, size_t ws_size,
                              hipStream_t stream) {
    const float* x  = (const float*)d_in[0];
    const int*   ei = (const int*)d_in[1];
    const int N = in_sizes[0] / C;
    const int E = in_sizes[1] / 2;
    const int* srcIdx = ei;
    const int* dstIdx = ei + E;

    // workspace layout
    char* w = (char*)d_ws;
    float* xs      = (float*)w; w += (size_t)N * C * 4;
    float* hbuf    = (float*)w; w += (size_t)N * C * 4;
    float* a_s     = (float*)w; w += (size_t)N * 4;
    float* a_d     = (float*)w; w += (size_t)N * 4;
    float* wvec    = (float*)w; w += C * 4;
    int*   dcount  = (int*)w;   w += (size_t)N * 4;
    int*   rowptr  = (int*)w;   w += ((size_t)N + 1) * 4;
    int*   cursor  = (int*)w;   w += (size_t)N * 4;
    int*   partials= (int*)w;   w += 256 * 4;
    int*   csr_src = (int*)w;   w += (size_t)E * 4;

    const float* Wsrc1 = (const float*)d_in[2];
    const float* Wdst1 = (const float*)d_in[3];
    const float* atts1 = (const float*)d_in[4];
    const float* attd1 = (const float*)d_in[5];
    const float* bcv1  = (const float*)d_in[6];
    const float* Wlin1 = (const float*)d_in[7];
    const float* blin1 = (const float*)d_in[8];
    const float* Wsrc2 = (const float*)d_in[9];
    const float* Wdst2 = (const float*)d_in[10];
    const float* atts2 = (const float*)d_in[11];
    const float* attd2 = (const float*)d_in[12];
    const float* bcv2  = (const float*)d_in[13];
    const float* Wlin2 = (const float*)d_in[14];
    const float* blin2 = (const float*)d_in[15];

    float* out = (float*)d_out;
    const int tblocks = (N + 63) / 64;
    const int nodeWaveBlocks = (N + 3) / 4;          // 1 wave per node, 4 waves/block
    const int nb = (N + 1023) / 1024;                // scan blocks (<=256 required)

    // ---------------- CSR build (per-call, deterministic) ----------------
    k_zero<<<512, 256, 0, stream>>>(dcount, N);
    k_hist<<<2048, 256, 0, stream>>>(dstIdx, dcount, E);
    k_scan_block<<<nb, 256, 0, stream>>>(dcount, rowptr, partials, N);
    k_scan_partials<<<1, 256, 0, stream>>>(partials, nb);
    k_scan_add<<<512, 256, 0, stream>>>(rowptr, cursor, partials, N, E);
    k_scatter<<<2048, 256, 0, stream>>>(srcIdx, dstIdx, cursor, csr_src, E);

    // ---------------- layer 1: x -> hbuf ----------------
    k_wvec<<<1, 64, 0, stream>>>(Wdst1, attd1, wvec);
    k_transform<<<tblocks, 256, 0, stream>>>(x, Wsrc1, Wlin1, atts1, wvec,
                                             bcv1, blin1, xs, a_s, a_d,
                                             hbuf, N);
    k_gat_node<<<nodeWaveBlocks, 256, 0, stream>>>(rowptr, csr_src, a_s, a_d,
                                                   xs, hbuf, N);

    // ---------------- layer 2: hbuf -> out ----------------
    k_wvec<<<1, 64, 0, stream>>>(Wdst2, attd2, wvec);
    k_transform<<<tblocks, 256, 0, stream>>>(hbuf, Wsrc2, Wlin2, atts2, wvec,
                                             bcv2, blin2, xs, a_s, a_d,
                                             out, N);
    k_gat_node<<<nodeWaveBlocks, 256, 0, stream>>>(rowptr, csr_src, a_s, a_d,
                                                   xs, out, N);

    // ---------------- final normalize ----------------
    k_normalize<<<1024, 256, 0, stream>>>(out, N);
}

// Round 5
// 454.784 us; speedup vs baseline: 3.9096x; 3.5413x over previous
//
#include <hip/hip_runtime.h>
#include <math.h>

#define C 64           // feature width for all layers
#define NEG_SLOPE 0.2f
#define LDP 68         // padded LDS row stride (floats): 68*4=272B, 16B-aligned

// ---- K0: wv[k] = sum_c W[k][c] * att[c]  (folds W_dst @ att_dst) ----
__global__ void k_wvec(const float* __restrict__ W, const float* __restrict__ att,
                       float* __restrict__ wv) {
    int k = threadIdx.x;  // 64 threads
    float s = 0.f;
    #pragma unroll
    for (int c = 0; c < C; ++c) s = fmaf(W[k * C + c], att[c], s);
    wv[k] = s;
}

// ---- K1: register-tiled dual GEMM per 64-node block, TWO PASSES to cap
//   register pressure (pass S: xs=x@Wsrc + a_s + a_d; pass L: outbuf=x@Wlin+bias)
// threads: 256 = (ty 0..15) x (tx 0..15); thread tile per pass: 4 rows x 4 cols
// k-loop: #pragma unroll 2 (NOT full) so the scheduler can't hoist 16 iters of
// ds_read_b128; __launch_bounds__(256,2) caps VGPR at 128.
__global__ __launch_bounds__(256, 2) void k_transform(
    const float* __restrict__ x,
    const float* __restrict__ Wsrc,
    const float* __restrict__ Wlin,
    const float* __restrict__ att_src,
    const float* __restrict__ wd,
    const float* __restrict__ b_conv,
    const float* __restrict__ b_lin,
    float* __restrict__ xs,
    float* __restrict__ a_s,
    float* __restrict__ a_d,
    float* __restrict__ outbuf,
    int nNodes)
{
    __shared__ float sWs[C * LDP];
    __shared__ float sWl[C * LDP];
    __shared__ float sx[C * LDP];
    __shared__ float swd[C];

    const int tid = threadIdx.x;
    const int tx = tid & 15;        // col group
    const int ty = tid >> 4;        // row group
    const int tx4 = tx * 4;
    const int n0 = blockIdx.x * 64; // first node of this block

    if (tid < C) swd[tid] = wd[tid];
    // stage W matrices (64x64, coalesced float4)
    #pragma unroll
    for (int j = 0; j < 4; ++j) {
        int idx = tid + j * 256;            // 1024 float4 slots
        int r = idx >> 4, q = idx & 15;
        *(float4*)&sWs[r * LDP + q * 4] = *(const float4*)&Wsrc[r * C + q * 4];
        *(float4*)&sWl[r * LDP + q * 4] = *(const float4*)&Wlin[r * C + q * 4];
    }
    // stage x tile (64 rows)
    #pragma unroll
    for (int j = 0; j < 4; ++j) {
        int idx = tid + j * 256;
        int r = idx >> 4, q = idx & 15;
        int n = n0 + r;
        float4 v = make_float4(0.f, 0.f, 0.f, 0.f);
        if (n < nNodes) v = *(const float4*)&x[(size_t)n * C + q * 4];
        *(float4*)&sx[r * LDP + q * 4] = v;
    }
    __syncthreads();

#define FMA4(XV, W, ACC)            \
    ACC.x = fmaf(XV, W.x, ACC.x);   \
    ACC.y = fmaf(XV, W.y, ACC.y);   \
    ACC.z = fmaf(XV, W.z, ACC.z);   \
    ACC.w = fmaf(XV, W.w, ACC.w);

    // ---------------- pass S: accS = x@Wsrc, ad = x.wd ----------------
    float4 accS0 = {0,0,0,0}, accS1 = {0,0,0,0}, accS2 = {0,0,0,0}, accS3 = {0,0,0,0};
    float ad0 = 0.f, ad1 = 0.f, ad2 = 0.f, ad3 = 0.f;

#define KSUB_S(COMP, KOFF)                                          \
    {                                                               \
        float4 ws = *(const float4*)&sWs[(k0 + KOFF) * LDP + tx4];  \
        float wdk = swd[k0 + KOFF];                                 \
        ad0 = fmaf(xr0.COMP, wdk, ad0); FMA4(xr0.COMP, ws, accS0)   \
        ad1 = fmaf(xr1.COMP, wdk, ad1); FMA4(xr1.COMP, ws, accS1)   \
        ad2 = fmaf(xr2.COMP, wdk, ad2); FMA4(xr2.COMP, ws, accS2)   \
        ad3 = fmaf(xr3.COMP, wdk, ad3); FMA4(xr3.COMP, ws, accS3)   \
    }

    #pragma unroll 2
    for (int k0 = 0; k0 < C; k0 += 4) {
        float4 xr0 = *(const float4*)&sx[(ty * 4 + 0) * LDP + k0];
        float4 xr1 = *(const float4*)&sx[(ty * 4 + 1) * LDP + k0];
        float4 xr2 = *(const float4*)&sx[(ty * 4 + 2) * LDP + k0];
        float4 xr3 = *(const float4*)&sx[(ty * 4 + 3) * LDP + k0];
        KSUB_S(x, 0)
        KSUB_S(y, 1)
        KSUB_S(z, 2)
        KSUB_S(w, 3)
    }
#undef KSUB_S

    // epilogue S: store xs, reduce a_s, store a_d
    {
        float4 attv = *(const float4*)&att_src[tx4];
#define EPI_S(R, AS, AD)                                                       \
        {                                                                      \
            int n = n0 + ty * 4 + R;                                           \
            if (n < nNodes) {                                                  \
                *(float4*)&xs[(size_t)n * C + tx4] = AS;                       \
                float p = AS.x * attv.x + AS.y * attv.y                        \
                        + AS.z * attv.z + AS.w * attv.w;                       \
                p += __shfl_xor(p, 8); p += __shfl_xor(p, 4);                  \
                p += __shfl_xor(p, 2); p += __shfl_xor(p, 1);                  \
                if (tx == 0) { a_s[n] = p; a_d[n] = AD; }                      \
            }                                                                  \
        }
        EPI_S(0, accS0, ad0)
        EPI_S(1, accS1, ad1)
        EPI_S(2, accS2, ad2)
        EPI_S(3, accS3, ad3)
#undef EPI_S
    }

    // ---------------- pass L: accL = x@Wlin + bias ----------------
    float4 accL0 = {0,0,0,0}, accL1 = {0,0,0,0}, accL2 = {0,0,0,0}, accL3 = {0,0,0,0};

#define KSUB_L(COMP, KOFF)                                          \
    {                                                               \
        float4 wl = *(const float4*)&sWl[(k0 + KOFF) * LDP + tx4];  \
        FMA4(xr0.COMP, wl, accL0)                                   \
        FMA4(xr1.COMP, wl, accL1)                                   \
        FMA4(xr2.COMP, wl, accL2)                                   \
        FMA4(xr3.COMP, wl, accL3)                                   \
    }

    #pragma unroll 2
    for (int k0 = 0; k0 < C; k0 += 4) {
        float4 xr0 = *(const float4*)&sx[(ty * 4 + 0) * LDP + k0];
        float4 xr1 = *(const float4*)&sx[(ty * 4 + 1) * LDP + k0];
        float4 xr2 = *(const float4*)&sx[(ty * 4 + 2) * LDP + k0];
        float4 xr3 = *(const float4*)&sx[(ty * 4 + 3) * LDP + k0];
        KSUB_L(x, 0)
        KSUB_L(y, 1)
        KSUB_L(z, 2)
        KSUB_L(w, 3)
    }
#undef KSUB_L
#undef FMA4

    // epilogue L
    {
        float4 bc = *(const float4*)&b_conv[tx4];
        float4 bl = *(const float4*)&b_lin[tx4];
        float4 bias = make_float4(bc.x + bl.x, bc.y + bl.y, bc.z + bl.z, bc.w + bl.w);
#define EPI_L(R, AL)                                                           \
        {                                                                      \
            int n = n0 + ty * 4 + R;                                           \
            if (n < nNodes) {                                                  \
                float4 vl = make_float4(AL.x + bias.x, AL.y + bias.y,          \
                                        AL.z + bias.z, AL.w + bias.w);         \
                *(float4*)&outbuf[(size_t)n * C + tx4] = vl;                   \
            }                                                                  \
        }
        EPI_L(0, accL0)
        EPI_L(1, accL1)
        EPI_L(2, accL2)
        EPI_L(3, accL3)
#undef EPI_L
    }
}

// ============================ CSR build ============================

__global__ __launch_bounds__(256) void k_zero(int* __restrict__ p, int n) {
    for (int i = blockIdx.x * blockDim.x + threadIdx.x; i < n;
         i += gridDim.x * blockDim.x) p[i] = 0;
}

__global__ __launch_bounds__(256) void k_hist(const int* __restrict__ dst,
                                              int* __restrict__ cnt, int nE) {
    for (int e = blockIdx.x * blockDim.x + threadIdx.x; e < nE;
         e += gridDim.x * blockDim.x) atomicAdd(&cnt[dst[e]], 1);
}

// block-level scan: 256 threads x 4 elems = 1024 per block
__global__ __launch_bounds__(256) void k_scan_block(
    const int* __restrict__ cnt, int* __restrict__ rowptr,
    int* __restrict__ partials, int n)
{
    __shared__ int sdata[256];
    const int base = blockIdx.x * 1024;
    const int t = threadIdx.x;
    int v[4]; int s = 0;
    #pragma unroll
    for (int i = 0; i < 4; ++i) {
        int idx = base + t * 4 + i;
        v[i] = (idx < n) ? cnt[idx] : 0;
        s += v[i];
    }
    sdata[t] = s;
    __syncthreads();
    for (int off = 1; off < 256; off <<= 1) {
        int x = (t >= off) ? sdata[t - off] : 0;
        __syncthreads();
        sdata[t] += x;
        __syncthreads();
    }
    int run = sdata[t] - s;   // exclusive prefix of this thread
    #pragma unroll
    for (int i = 0; i < 4; ++i) {
        int idx = base + t * 4 + i;
        if (idx < n) rowptr[idx] = run;
        run += v[i];
    }
    if (t == 255) partials[blockIdx.x] = sdata[255];
}

// single-block exclusive scan of <=256 partials
__global__ __launch_bounds__(256) void k_scan_partials(int* __restrict__ partials, int nb) {
    __shared__ int sd[256];
    const int t = threadIdx.x;
    int v = (t < nb) ? partials[t] : 0;
    sd[t] = v;
    __syncthreads();
    for (int off = 1; off < 256; off <<= 1) {
        int x = (t >= off) ? sd[t - off] : 0;
        __syncthreads();
        sd[t] += x;
        __syncthreads();
    }
    if (t < nb) partials[t] = sd[t] - v;   // exclusive
}

__global__ __launch_bounds__(256) void k_scan_add(
    int* __restrict__ rowptr, int* __restrict__ cursor,
    const int* __restrict__ partials, int n, int nE)
{
    for (int i = blockIdx.x * blockDim.x + threadIdx.x; i < n;
         i += gridDim.x * blockDim.x) {
        int r = rowptr[i] + partials[i >> 10];
        rowptr[i] = r;
        cursor[i] = r;
    }
    if (blockIdx.x == 0 && threadIdx.x == 0) rowptr[n] = nE;
}

__global__ __launch_bounds__(256) void k_scatter(
    const int* __restrict__ src, const int* __restrict__ dst,
    int* __restrict__ cursor, int* __restrict__ csr_src, int nE)
{
    for (int e = blockIdx.x * blockDim.x + threadIdx.x; e < nE;
         e += gridDim.x * blockDim.x) {
        int pos = atomicAdd(&cursor[dst[e]], 1);
        csr_src[pos] = src[e];
    }
}

// ============== fused per-dst-node GAT aggregation ==============
__global__ __launch_bounds__(256) void k_gat_node(
    const int* __restrict__ rowptr, const int* __restrict__ csr_src,
    const float* __restrict__ a_s, const float* __restrict__ a_d,
    const float* __restrict__ xs, float* __restrict__ outbuf, int nNodes)
{
    const int lane = threadIdx.x & 63;
    const int n = (blockIdx.x * blockDim.x + threadIdx.x) >> 6;
    if (n >= nNodes) return;
    const int start = rowptr[n], end = rowptr[n + 1];
    if (start == end) return;            // keep the linear-skip part only
    const float a_dn = a_d[n];

    // pass 1: segment max
    float mloc = -INFINITY;
    for (int j = start + lane; j < end; j += 64) {
        float ev = a_s[csr_src[j]] + a_dn;
        ev = ev > 0.f ? ev : NEG_SLOPE * ev;
        mloc = fmaxf(mloc, ev);
    }
    #pragma unroll
    for (int m = 32; m > 0; m >>= 1) mloc = fmaxf(mloc, __shfl_xor(mloc, m));

    // pass 2+3
    float acc = 0.f;
    float sloc = 0.f;
    for (int jb = start; jb < end; jb += 64) {
        const int cnt = min(64, end - jb);
        float ex = 0.f; int sidx = 0;
        if (lane < cnt) {
            sidx = csr_src[jb + lane];
            float ev = a_s[sidx] + a_dn;
            ev = ev > 0.f ? ev : NEG_SLOPE * ev;
            ex = __expf(ev - mloc);
            sloc += ex;
        }
        int t = 0;
        for (; t + 1 < cnt; t += 2) {
            float w0 = __shfl(ex, t);     int s0 = __shfl(sidx, t);
            float w1 = __shfl(ex, t + 1); int s1 = __shfl(sidx, t + 1);
            float v0 = xs[(size_t)s0 * C + lane];
            float v1 = xs[(size_t)s1 * C + lane];
            acc = fmaf(w0, v0, acc);
            acc = fmaf(w1, v1, acc);
        }
        if (t < cnt) {
            float w0 = __shfl(ex, t); int s0 = __shfl(sidx, t);
            acc = fmaf(w0, xs[(size_t)s0 * C + lane], acc);
        }
    }
    #pragma unroll
    for (int m = 32; m > 0; m >>= 1) sloc += __shfl_xor(sloc, m);

    outbuf[(size_t)n * C + lane] += acc / sloc;
}

// ---- K5: row L2-normalize, in place ----
__global__ __launch_bounds__(256) void k_normalize(float* __restrict__ out, int nNodes)
{
    const int lane = threadIdx.x & 63;
    const int grp  = threadIdx.x >> 6;
    const int groups = gridDim.x * (blockDim.x >> 6);
    for (int n = blockIdx.x * (blockDim.x >> 6) + grp; n < nNodes; n += groups) {
        float v = out[(size_t)n * C + lane];
        float ss = v * v;
        #pragma unroll
        for (int m = 32; m > 0; m >>= 1) ss += __shfl_xor(ss, m);
        float nrm = fmaxf(sqrtf(ss), 1e-12f);
        out[(size_t)n * C + lane] = v / nrm;
    }
}

extern "C" void kernel_launch(void* const* d_in, const int* in_sizes, int n_in,
                              void* d_out, int out_size, void* d_ws, size_t ws_size,
                              hipStream_t stream) {
    const float* x  = (const float*)d_in[0];
    const int*   ei = (const int*)d_in[1];
    const int N = in_sizes[0] / C;
    const int E = in_sizes[1] / 2;
    const int* srcIdx = ei;
    const int* dstIdx = ei + E;

    // workspace layout
    char* w = (char*)d_ws;
    float* xs      = (float*)w; w += (size_t)N * C * 4;
    float* hbuf    = (float*)w; w += (size_t)N * C * 4;
    float* a_s     = (float*)w; w += (size_t)N * 4;
    float* a_d     = (float*)w; w += (size_t)N * 4;
    float* wvec    = (float*)w; w += C * 4;
    int*   dcount  = (int*)w;   w += (size_t)N * 4;
    int*   rowptr  = (int*)w;   w += ((size_t)N + 1) * 4;
    int*   cursor  = (int*)w;   w += (size_t)N * 4;
    int*   partials= (int*)w;   w += 256 * 4;
    int*   csr_src = (int*)w;   w += (size_t)E * 4;

    const float* Wsrc1 = (const float*)d_in[2];
    const float* Wdst1 = (const float*)d_in[3];
    const float* atts1 = (const float*)d_in[4];
    const float* attd1 = (const float*)d_in[5];
    const float* bcv1  = (const float*)d_in[6];
    const float* Wlin1 = (const float*)d_in[7];
    const float* blin1 = (const float*)d_in[8];
    const float* Wsrc2 = (const float*)d_in[9];
    const float* Wdst2 = (const float*)d_in[10];
    const float* atts2 = (const float*)d_in[11];
    const float* attd2 = (const float*)d_in[12];
    const float* bcv2  = (const float*)d_in[13];
    const float* Wlin2 = (const float*)d_in[14];
    const float* blin2 = (const float*)d_in[15];

    float* out = (float*)d_out;
    const int tblocks = (N + 63) / 64;
    const int nodeWaveBlocks = (N + 3) / 4;          // 1 wave per node, 4 waves/block
    const int nb = (N + 1023) / 1024;                // scan blocks (<=256 required)

    // ---------------- CSR build (per-call, deterministic) ----------------
    k_zero<<<512, 256, 0, stream>>>(dcount, N);
    k_hist<<<2048, 256, 0, stream>>>(dstIdx, dcount, E);
    k_scan_block<<<nb, 256, 0, stream>>>(dcount, rowptr, partials, N);
    k_scan_partials<<<1, 256, 0, stream>>>(partials, nb);
    k_scan_add<<<512, 256, 0, stream>>>(rowptr, cursor, partials, N, E);
    k_scatter<<<2048, 256, 0, stream>>>(srcIdx, dstIdx, cursor, csr_src, E);

    // ---------------- layer 1: x -> hbuf ----------------
    k_wvec<<<1, 64, 0, stream>>>(Wdst1, attd1, wvec);
    k_transform<<<tblocks, 256, 0, stream>>>(x, Wsrc1, Wlin1, atts1, wvec,
                                             bcv1, blin1, xs, a_s, a_d,
                                             hbuf, N);
    k_gat_node<<<nodeWaveBlocks, 256, 0, stream>>>(rowptr, csr_src, a_s, a_d,
                                                   xs, hbuf, N);

    // ---------------- layer 2: hbuf -> out ----------------
    k_wvec<<<1, 64, 0, stream>>>(Wdst2, attd2, wvec);
    k_transform<<<tblocks, 256, 0, stream>>>(hbuf, Wsrc2, Wlin2, atts2, wvec,
                                             bcv2, blin2, xs, a_s, a_d,
                                             out, N);
    k_gat_node<<<nodeWaveBlocks, 256, 0, stream>>>(rowptr, csr_src, a_s, a_d,
                                                   xs, out, N);

    // ---------------- final normalize ----------------
    k_normalize<<<1024, 256, 0, stream>>>(out, N);
}